// Round 1
// baseline (9102.483 us; speedup 1.0000x reference)
//
#include <hip/hip_runtime.h>
#include <stdint.h>

#define T_DIM 1024
#define E_DIM 768
#define H_DIM 6
#define HD_DIM 128
#define HID_DIM 3072
#define V_DIM 50304
#define NL 12
#define EPS_F 1e-6f

typedef __attribute__((ext_vector_type(8))) short s8v;
typedef __attribute__((ext_vector_type(4))) float f4v;

// ---------- helpers ----------
__device__ __forceinline__ ushort f2bf(float x){
  uint32_t u = __float_as_uint(x);
  u += 0x7fffu + ((u >> 16) & 1u);          // round-to-nearest-even
  return (ushort)(u >> 16);
}
__device__ __forceinline__ float bf2f(ushort h){ return __uint_as_float(((uint32_t)h) << 16); }
// packed split32: low16 = bf16(hi), high16 = bf16(x - hi)
__device__ __forceinline__ uint32_t pack_split(float x){
  ushort h = f2bf(x);
  ushort l = f2bf(x - bf2f(h));
  return (uint32_t)h | ((uint32_t)l << 16);
}

template<int OP>  // 0=sum 1=max, block of 256 threads
__device__ __forceinline__ float block_red(float v){
  __shared__ float red[4];
  #pragma unroll
  for (int o = 32; o; o >>= 1){
    float t = __shfl_xor(v, o, 64);
    v = OP ? fmaxf(v, t) : (v + t);
  }
  __syncthreads();
  if ((threadIdx.x & 63) == 0) red[threadIdx.x >> 6] = v;
  __syncthreads();
  return OP ? fmaxf(fmaxf(red[0], red[1]), fmaxf(red[2], red[3]))
            : (red[0] + red[1] + red[2] + red[3]);
}

// ---------- embedding + rmsnorm ----------
__global__ __launch_bounds__(256) void embed_norm_k(const int* __restrict__ idx,
    const float* __restrict__ wte, float* __restrict__ x, float* __restrict__ x0){
  const int row = blockIdx.x, t = threadIdx.x;
  const float* src = wte + (long)idx[row] * E_DIM;
  float v0 = src[t], v1 = src[t + 256], v2 = src[t + 512];
  float ss = block_red<0>(v0*v0 + v1*v1 + v2*v2);
  float r = rsqrtf(ss * (1.f / E_DIM) + EPS_F);
  long base = (long)row * E_DIM;
  float y0 = v0*r, y1 = v1*r, y2 = v2*r;
  x[base+t] = y0; x[base+t+256] = y1; x[base+t+512] = y2;
  x0[base+t] = y0; x0[base+t+256] = y1; x0[base+t+512] = y2;
}

// ---------- (optional residual mix) + rmsnorm -> split32 ----------
__global__ __launch_bounds__(256) void norm_split_k(float* __restrict__ x,
    const float* __restrict__ x0, const float* __restrict__ rl, const float* __restrict__ xl,
    int layer, uint32_t* __restrict__ h, int mix){
  const int row = blockIdx.x, t = threadIdx.x;
  const long base = (long)row * E_DIM;
  float a = 1.f, b = 0.f;
  if (mix){ a = rl[layer]; b = xl[layer]; }
  float v[3]; float ss = 0.f;
  #pragma unroll
  for (int j = 0; j < 3; j++){
    float xv = x[base + t + 256*j];
    if (mix) xv = a*xv + b*x0[base + t + 256*j];
    v[j] = xv; ss += xv*xv;
  }
  ss = block_red<0>(ss);
  float r = rsqrtf(ss * (1.f / E_DIM) + EPS_F);
  #pragma unroll
  for (int j = 0; j < 3; j++){
    if (mix) x[base + t + 256*j] = v[j];
    h[base + t + 256*j] = pack_split(v[j] * r);
  }
}

// ---------- RoPE + per-head rmsnorm: (B,T,E) f32 -> (B,H,T,HD) split32 ----------
__global__ __launch_bounds__(256) void rope_norm_k(const float* __restrict__ wq,
    uint32_t* __restrict__ w){
  const int wv = threadIdx.x >> 6, d = threadIdx.x & 63;
  const int rid = blockIdx.x * 4 + wv;                  // (b,t,h) flat
  const int b = rid / (T_DIM * H_DIM);
  const int rem = rid % (T_DIM * H_DIM);
  const int t = rem / H_DIM, hh = rem % H_DIM;
  const long ib = ((long)(b * T_DIM + t)) * E_DIM + hh * HD_DIM;
  float x1 = wq[ib + d], x2 = wq[ib + d + 64];
  float inv = exp2f(-13.28771237954945f * (float)d * (1.f / 64.f)); // 10000^(-d/64)
  float fr = (float)t * inv;
  float c = cosf(fr), s = sinf(fr);
  float y1 =  x1*c + x2*s;
  float y2 = -x1*s + x2*c;
  float ss = y1*y1 + y2*y2;
  #pragma unroll
  for (int o = 32; o; o >>= 1) ss += __shfl_xor(ss, o, 64);
  float r = rsqrtf(ss * (1.f / HD_DIM) + EPS_F);
  const long ob = ((long)((b * H_DIM + hh) * T_DIM + t)) * HD_DIM + d;
  w[ob]      = pack_split(y1 * r);
  w[ob + 64] = pack_split(y2 * r);
}

// ---------- causal row softmax; reads f32 S, writes split32 P in place ----------
__global__ __launch_bounds__(256) void softmax_k(float* __restrict__ SP){
  const int q = blockIdx.x, bh = blockIdx.y, t = threadIdx.x;
  float* Srow = SP + ((long)bh * T_DIM + q) * T_DIM;
  __shared__ float buf[T_DIM];
  const int n  = q + 1;
  const int nk = ((q >> 7) + 1) << 7;                   // pad to k-tile boundary
  const float scale = 0.08838834764831845f;             // 1/sqrt(128)
  float mx = -3.4e38f;
  for (int k = t; k < n; k += 256){ float v = Srow[k] * scale; buf[k] = v; mx = fmaxf(mx, v); }
  mx = block_red<1>(mx);
  float sum = 0.f;
  for (int k = t; k < n; k += 256){
    float e = exp2f((buf[k] - mx) * 1.4426950408889634f);
    buf[k] = e; sum += e;
  }
  sum = block_red<0>(sum);
  float invs = 1.f / sum;
  uint32_t* P = (uint32_t*)Srow;
  for (int k = t; k < n; k += 256) P[k] = pack_split(buf[k] * invs);
  for (int k = n + t; k < nk; k += 256) P[k] = 0u;
}

// ---------- templated 128x128 split-bf16 NT GEMM ----------
#define EPI_F32 0
#define EPI_ADD 1
#define EPI_RELU_SPLIT 2
#define EPI_SPLIT 3
#define BM_CONV 0      // B = f32 [n][k]
#define BM_SPLIT 1     // B = split32 [n][k]
#define BM_SPLIT_NN 2  // B = split32 [k][n]

template<int EPI, int BMODE, bool SPLIT, bool CN, bool CK>
__global__ __launch_bounds__(256) void gemm_k(
    const uint32_t* __restrict__ Ab, const void* __restrict__ Bb,
    void* __restrict__ Cb, const float* __restrict__ thrp,
    int K, int lda, int ldb, int ldc,
    long sAz, long sBz, int cdiv, long cs1, long cs2, int mtiles)
{
  __shared__ ushort sA[2][128][40];   // [hi/lo][m][k] pad+8 keeps 16B rows (80B)
  __shared__ ushort sB[2][128][40];
  const int tid = threadIdx.x;
  const int lane = tid & 63, wave = tid >> 6;
  const int wm = wave >> 1, wn = wave & 1;
  const int fr = lane & 15, kq = lane >> 4;
  const int z = blockIdx.z;
  const uint32_t* A0 = Ab + (long)z * sAz;
  const char* Bz = (const char*)Bb + (long)z * sBz * 4;
  const long coff = (long)(z / cdiv) * cs1 + (long)(z % cdiv) * cs2;
  const int n0 = blockIdx.x * 128;

  for (int mtt = 0; mtt < mtiles; ++mtt) {
    const int mt = blockIdx.y * mtiles + mtt;
    if (CN && (int)blockIdx.x > mt) return;             // causal upper tiles
    const int m0 = mt * 128;

    f4v acc[4][4];
    #pragma unroll
    for (int i = 0; i < 4; i++)
      #pragma unroll
      for (int j = 0; j < 4; j++) acc[i][j] = (f4v){0.f, 0.f, 0.f, 0.f};

    int ktiles = K >> 5;
    if (CK){ int lim = (mt + 1) * 4; if (lim < ktiles) ktiles = lim; }

    for (int kt = 0; kt < ktiles; ++kt) {
      const int k0 = kt * 32;
      __syncthreads();
      // ---- stage A (split32 [m][k]) ----
      #pragma unroll
      for (int j = 0; j < 4; j++){
        const int v = tid + 256 * j;
        const int r = v >> 3, c4 = (v & 7) << 2;
        const uint4 wv = *(const uint4*)(A0 + (long)(m0 + r) * lda + k0 + c4);
        uint2 hv; hv.x = (wv.x & 0xffffu) | (wv.y << 16);
                  hv.y = (wv.z & 0xffffu) | (wv.w << 16);
        *(uint2*)&sA[0][r][c4] = hv;
        if (SPLIT){
          uint2 lv; lv.x = (wv.x >> 16) | (wv.y & 0xffff0000u);
                    lv.y = (wv.z >> 16) | (wv.w & 0xffff0000u);
          *(uint2*)&sA[1][r][c4] = lv;
        }
      }
      // ---- stage B ----
      if (BMODE == BM_SPLIT){
        const uint32_t* Bu = (const uint32_t*)Bz;
        #pragma unroll
        for (int j = 0; j < 4; j++){
          const int v = tid + 256 * j;
          const int r = v >> 3, c4 = (v & 7) << 2;
          const uint4 wv = *(const uint4*)(Bu + (long)(n0 + r) * ldb + k0 + c4);
          uint2 hv; hv.x = (wv.x & 0xffffu) | (wv.y << 16);
                    hv.y = (wv.z & 0xffffu) | (wv.w << 16);
          *(uint2*)&sB[0][r][c4] = hv;
          if (SPLIT){
            uint2 lv; lv.x = (wv.x >> 16) | (wv.y & 0xffff0000u);
                      lv.y = (wv.z >> 16) | (wv.w & 0xffff0000u);
            *(uint2*)&sB[1][r][c4] = lv;
          }
        }
      } else if (BMODE == BM_CONV){
        const float* Bf = (const float*)Bz;
        #pragma unroll
        for (int j = 0; j < 4; j++){
          const int v = tid + 256 * j;
          const int r = v >> 3, c4 = (v & 7) << 2;
          const float4 f = *(const float4*)(Bf + (long)(n0 + r) * ldb + k0 + c4);
          uint32_t p0, p1, p2, p3;
          if (SPLIT){ p0 = pack_split(f.x); p1 = pack_split(f.y);
                      p2 = pack_split(f.z); p3 = pack_split(f.w); }
          else      { p0 = f2bf(f.x); p1 = f2bf(f.y); p2 = f2bf(f.z); p3 = f2bf(f.w); }
          uint2 hv; hv.x = (p0 & 0xffffu) | (p1 << 16);
                    hv.y = (p2 & 0xffffu) | (p3 << 16);
          *(uint2*)&sB[0][r][c4] = hv;
          if (SPLIT){
            uint2 lv; lv.x = (p0 >> 16) | (p1 & 0xffff0000u);
                      lv.y = (p2 >> 16) | (p3 & 0xffff0000u);
            *(uint2*)&sB[1][r][c4] = lv;
          }
        }
      } else { // BM_SPLIT_NN: B split32 [k][n] -> transpose into LDS
        const uint32_t* Bu = (const uint32_t*)Bz;
        #pragma unroll
        for (int j = 0; j < 4; j++){
          const int v = tid + 256 * j;
          const int kr = v >> 5, c4 = (v & 31) << 2;
          const uint4 wv = *(const uint4*)(Bu + (long)(k0 + kr) * ldb + n0 + c4);
          uint32_t ww[4] = {wv.x, wv.y, wv.z, wv.w};
          #pragma unroll
          for (int q = 0; q < 4; q++){
            sB[0][c4 + q][kr] = (ushort)(ww[q] & 0xffffu);
            if (SPLIT) sB[1][c4 + q][kr] = (ushort)(ww[q] >> 16);
          }
        }
      }
      __syncthreads();
      // ---- fragments + MFMA ----
      s8v afr[2][4], bfr[2][4];
      #pragma unroll
      for (int i = 0; i < 4; i++){
        afr[0][i] = *(const s8v*)&sA[0][wm*64 + i*16 + fr][kq*8];
        bfr[0][i] = *(const s8v*)&sB[0][wn*64 + i*16 + fr][kq*8];
        if (SPLIT){
          afr[1][i] = *(const s8v*)&sA[1][wm*64 + i*16 + fr][kq*8];
          bfr[1][i] = *(const s8v*)&sB[1][wn*64 + i*16 + fr][kq*8];
        }
      }
      #pragma unroll
      for (int i = 0; i < 4; i++)
        #pragma unroll
        for (int j = 0; j < 4; j++){
          acc[i][j] = __builtin_amdgcn_mfma_f32_16x16x32_bf16(afr[0][i], bfr[0][j], acc[i][j], 0, 0, 0);
          if (SPLIT){
            acc[i][j] = __builtin_amdgcn_mfma_f32_16x16x32_bf16(afr[1][i], bfr[0][j], acc[i][j], 0, 0, 0);
            acc[i][j] = __builtin_amdgcn_mfma_f32_16x16x32_bf16(afr[0][i], bfr[1][j], acc[i][j], 0, 0, 0);
          }
        }
    }
    // ---- epilogue (C/D: col=lane&15, row=(lane>>4)*4+reg) ----
    const int r0 = m0 + wm * 64, c0 = n0 + wn * 64;
    #pragma unroll
    for (int i = 0; i < 4; i++)
      #pragma unroll
      for (int j = 0; j < 4; j++)
        #pragma unroll
        for (int rr = 0; rr < 4; rr++){
          const int row = r0 + i*16 + kq*4 + rr;
          const int col = c0 + j*16 + fr;
          const long off = coff + (long)row * ldc + col;
          const float vv = acc[i][j][rr];
          if (EPI == EPI_F32)        ((float*)Cb)[off] = vv;
          else if (EPI == EPI_ADD)   ((float*)Cb)[off] += vv;
          else if (EPI == EPI_SPLIT) ((uint32_t*)Cb)[off] = pack_split(vv);
          else { float u = vv - thrp[col]; ((uint32_t*)Cb)[off] = pack_split(fmaxf(u, 0.f)); }
        }
  }
}

// ---------- launcher ----------
extern "C" void kernel_launch(void* const* d_in, const int* in_sizes, int n_in,
                              void* d_out, int out_size, void* d_ws, size_t ws_size,
                              hipStream_t stream) {
  (void)in_sizes; (void)n_in; (void)out_size; (void)ws_size;
  const int*   idx    = (const int*)  d_in[0];
  const float* wte    = (const float*)d_in[1];
  const float* lmw    = (const float*)d_in[2];
  const float* qkvw   = (const float*)d_in[3];
  const float* cprojw = (const float*)d_in[4];
  const float* dencw  = (const float*)d_in[5];
  const float* ddecw  = (const float*)d_in[6];
  const float* thr    = (const float*)d_in[7];
  const float* rl     = (const float*)d_in[8];
  const float* xl     = (const float*)d_in[9];
  float* out = (float*)d_out;

  char* p = (char*)d_ws;
  const long BT = 4096;
  float*    x  = (float*)p;    p += BT * E_DIM * 4;
  float*    x0 = (float*)p;    p += BT * E_DIM * 4;
  uint32_t* h  = (uint32_t*)p; p += BT * E_DIM * 4;
  float*    wq = (float*)p;    p += BT * E_DIM * 4;
  uint32_t* w  = (uint32_t*)p; p += BT * E_DIM * 4;
  uint32_t* o  = (uint32_t*)p; p += BT * E_DIM * 4;
  uint32_t* a  = (uint32_t*)p; p += BT * (long)HID_DIM * 4;
  float*    S  = (float*)p;    p += (long)24 * T_DIM * T_DIM * 4;   // aliased by P

  embed_norm_k<<<4096, 256, 0, stream>>>(idx, wte, x, x0);

  for (int i = 0; i < NL; i++){
    norm_split_k<<<4096, 256, 0, stream>>>(x, x0, rl, xl, i, h, 1);
    // qkv: (4096x768) @ (768x768)^T -> wq f32
    gemm_k<EPI_F32, BM_CONV, true, false, false><<<dim3(6,32,1), 256, 0, stream>>>(
        h, qkvw + (long)i*E_DIM*E_DIM, wq, nullptr, E_DIM, E_DIM, E_DIM, E_DIM,
        0, 0, 1, 0, 0, 1);
    rope_norm_k<<<6144, 256, 0, stream>>>(wq, w);
    // scores: per (b,h): (1024x128)@(1024x128)^T -> S f32 (causal tiles only)
    gemm_k<EPI_F32, BM_SPLIT, true, true, false><<<dim3(8,8,24), 256, 0, stream>>>(
        w, w, S, nullptr, HD_DIM, HD_DIM, HD_DIM, T_DIM,
        (long)T_DIM*HD_DIM, (long)T_DIM*HD_DIM, 1, (long)T_DIM*T_DIM, 0, 1);
    softmax_k<<<dim3(1024,24), 256, 0, stream>>>(S);
    // PV: per (b,h): P(1024x1024) @ V(1024x128) -> o split32 (B,T,E)
    gemm_k<EPI_SPLIT, BM_SPLIT_NN, true, false, true><<<dim3(1,8,24), 256, 0, stream>>>(
        (const uint32_t*)S, w, o, nullptr, T_DIM, T_DIM, HD_DIM, E_DIM,
        (long)T_DIM*T_DIM, (long)T_DIM*HD_DIM, H_DIM, (long)T_DIM*E_DIM, HD_DIM, 1);
    // cproj: x += o @ cproj^T
    gemm_k<EPI_ADD, BM_CONV, true, false, false><<<dim3(6,32,1), 256, 0, stream>>>(
        o, cprojw + (long)i*E_DIM*E_DIM, x, nullptr, E_DIM, E_DIM, E_DIM, E_DIM,
        0, 0, 1, 0, 0, 1);
    norm_split_k<<<4096, 256, 0, stream>>>(x, x0, rl, xl, i, h, 0);
    // denc: a = relu(h2 @ denc^T - thr) -> split32
    gemm_k<EPI_RELU_SPLIT, BM_CONV, true, false, false><<<dim3(24,32,1), 256, 0, stream>>>(
        h, dencw + (long)i*HID_DIM*E_DIM, a, thr + (long)i*HID_DIM,
        E_DIM, E_DIM, E_DIM, HID_DIM, 0, 0, 1, 0, 0, 1);
    // ddec: x += a @ ddec^T
    gemm_k<EPI_ADD, BM_CONV, true, false, false><<<dim3(6,32,1), 256, 0, stream>>>(
        a, ddecw + (long)i*E_DIM*HID_DIM, x, nullptr, HID_DIM, HID_DIM, HID_DIM, E_DIM,
        0, 0, 1, 0, 0, 1);
  }

  norm_split_k<<<4096, 256, 0, stream>>>(x, x0, rl, xl, 0, h, 0);
  // lm_head: plain bf16, persistent over N: grid (393 n-tiles, 2 m-halves), 16 m-tiles each
  gemm_k<EPI_F32, BM_CONV, false, false, false><<<dim3(393,2,1), 256, 0, stream>>>(
      h, lmw, out, nullptr, E_DIM, E_DIM, E_DIM, V_DIM, 0, 0, 1, 0, 0, 16);
}